// Round 11
// baseline (173.553 us; speedup 1.0000x reference)
//
#include <hip/hip_runtime.h>
#include <hip/hip_bf16.h>

typedef __attribute__((ext_vector_type(8))) __bf16 bf16x8;
typedef __attribute__((ext_vector_type(4))) float f32x4;

#define DDIM 256
#define KCENT 1024
#define BM 64
#define BN 64
#define ROWB 512              // row stride: 256 bf16 = 512 B
#define NTILES (KCENT / BN)   // 16
#define BUFB 32768            // one B buffer: 64 rows x 512 B

union FragU { uint4 u; bf16x8 f; };

__device__ __forceinline__ unsigned int pk2(float lo, float hi) {
    union { __hip_bfloat16 h; unsigned short u; } a, b;
    a.h = __float2bfloat16(lo);
    b.h = __float2bfloat16(hi);
    return (unsigned int)a.u | ((unsigned int)b.u << 16);
}

__device__ __forceinline__ void gl_lds16(const void* g, void* l) {
    __builtin_amdgcn_global_load_lds(
        (const __attribute__((address_space(1))) unsigned int*)g,
        (__attribute__((address_space(3))) unsigned int*)l,
        16, 0, 0);
}

// ---------------------------------------------------------------------------
// Kernel 1 (unchanged, validated): centers f32 -> bf16 + exact f32 stats.
// ---------------------------------------------------------------------------
__global__ __launch_bounds__(256) void rbf_prep_c(
    const float* __restrict__ centers, const float* __restrict__ sigmas,
    __bf16* __restrict__ cbf, float2* __restrict__ c2s)
{
    const int wave = threadIdx.x >> 6, lane = threadIdx.x & 63;
    const int r = blockIdx.x * 4 + wave;

    const float4* __restrict__ src = (const float4*)(centers + (size_t)r * DDIM);
    const float4 v = src[lane];
    float s = v.x * v.x + v.y * v.y + v.z * v.z + v.w * v.w;
#pragma unroll
    for (int m = 1; m < 64; m <<= 1) s += __shfl_xor(s, m, 64);

    uint2 p;
    p.x = pk2(v.x, v.y);
    p.y = pk2(v.z, v.w);
    ((uint2*)(cbf + (size_t)r * DDIM))[lane] = p;

    if (lane == 0) {
        const float sg = sigmas[r];
        c2s[r] = make_float2(s, -0.5f / (sg * sg));
    }
}

// ---------------------------------------------------------------------------
// Kernel 2 (R11): A-in-registers + double-buffered B + ONE sync per tile.
// 64-row M-panel per block, N-loop inside, 256 threads (2x2 waves of 32x32),
// LDS = 2 x 32 KB B buffers -> 2 blocks/CU (two barrier domains, m114).
// A: each lane converts exactly its MFMA A-fragment elements from global f32
//    (row wr*32+fm*16+r16, k = kw*32+q*8..+8) into 64 VGPRs of bf16, summing
//    x^2 in f32 on the way (q-reduce via shfl_xor ^16/^32). No A staging, no
//    A LDS, no A ds_reads -> LDS read traffic halved vs R10.
// B: validated gl_lds16 + pre-swizzled source (XOR-low-3 involution, 0
//    conflicts R4-R10); prefetch B[nt+1] into the idle buffer at tile START,
//    drained by the single end-of-tile __syncthreads (~2000 cyc of flight).
//    Buffer safety: buf[(nt+1)&1] last read in tile nt-1, fenced by its sync.
// MFMA fragment + C/D epilogue mappings verbatim (absmax 0.0 on HW, 5 rounds).
// ---------------------------------------------------------------------------
__global__ __launch_bounds__(256, 2) void rbf_gemm(
    const float* __restrict__ x, const __bf16* __restrict__ cbf,
    const float2* __restrict__ c2s, float* __restrict__ out)
{
    __shared__ __align__(16) unsigned char ldsB[2 * BUFB];  // 64 KB
    __shared__ float s_x2[BM];

    const int t = threadIdx.x;
    const int lane = t & 63, wave = t >> 6;
    const int wr = wave >> 1, wc = wave & 1;       // 2x2 wave grid, 32x32 each
    const int q = lane >> 4, r16 = lane & 15;
    const int mrow0 = blockIdx.x * BM;

    const char* __restrict__ cg = (const char*)cbf;

    // B staging role: issue i covers LDS [i*4096,+4096): row = i*8 + (t>>5),
    // chunk = t&31; source chunk pre-swizzled by row&7 (rule #21).
    const int srow = t >> 5;
    const int schunk = t & 31;

    // ---- issue B[0] -> buf0 (flight covers the whole A conversion) ----
#pragma unroll
    for (int i = 0; i < 8; ++i) {
        const int row = i * 8 + srow;
        const int chunk = schunk ^ (row & 7);
        gl_lds16(cg + (size_t)row * ROWB + chunk * 16,
                 ldsB + i * 4096 + (wave << 10));
    }

    // ---- A fragments straight from global f32 -> bf16 registers ----
    FragU afr[2][8];
    float s0 = 0.f, s1 = 0.f;
#pragma unroll
    for (int fm = 0; fm < 2; ++fm) {
        const float* __restrict__ rowp =
            x + (size_t)(mrow0 + wr * 32 + fm * 16 + r16) * DDIM + q * 8;
#pragma unroll
        for (int kw = 0; kw < 8; ++kw) {
            const float4 v0 = *(const float4*)(rowp + kw * 32);
            const float4 v1 = *(const float4*)(rowp + kw * 32 + 4);
            const float s = v0.x * v0.x + v0.y * v0.y + v0.z * v0.z + v0.w * v0.w
                          + v1.x * v1.x + v1.y * v1.y + v1.z * v1.z + v1.w * v1.w;
            if (fm == 0) s0 += s; else s1 += s;
            afr[fm][kw].u = make_uint4(pk2(v0.x, v0.y), pk2(v0.z, v0.w),
                                       pk2(v1.x, v1.y), pk2(v1.z, v1.w));
        }
    }
    // q-reduce (q = lane>>4; lanes ^16 and ^32 span q) -> full 256-elem row sums
    s0 += __shfl_xor(s0, 16, 64); s0 += __shfl_xor(s0, 32, 64);
    s1 += __shfl_xor(s1, 16, 64); s1 += __shfl_xor(s1, 32, 64);
    if (wc == 0 && q == 0) {
        s_x2[wr * 32 + r16] = s0;
        s_x2[wr * 32 + 16 + r16] = s1;
    }

    __syncthreads();  // B[0] landed (vmcnt drain); s_x2 visible

    // epilogue row stats to regs (rows il0+fm*16+rg, per C/D layout)
    const int il0 = wr * 32 + q * 4;
    float xr[2][4];
#pragma unroll
    for (int fm = 0; fm < 2; ++fm)
#pragma unroll
        for (int rg = 0; rg < 4; ++rg)
            xr[fm][rg] = s_x2[il0 + fm * 16 + rg];

    float* outbase = out + (size_t)mrow0 * KCENT;

    for (int nt = 0; nt < NTILES; ++nt) {
        // ---- prefetch B[nt+1] into the idle buffer (freed by sync of nt-1) ----
        if (nt + 1 < NTILES) {
            unsigned char* dst = ldsB + ((nt + 1) & 1) * BUFB;
#pragma unroll
            for (int i = 0; i < 8; ++i) {
                const int row = i * 8 + srow;
                const int chunk = schunk ^ (row & 7);
                gl_lds16(cg + (size_t)((nt + 1) * BN + row) * ROWB + chunk * 16,
                         dst + i * 4096 + (wave << 10));
            }
        }

        // ---- 8 K-windows x {2 ds_read_b128 + 4 MFMA} from buf[nt&1] ----
        const unsigned char* buf = ldsB + (nt & 1) * BUFB;
        f32x4 acc[2][2];
#pragma unroll
        for (int fm = 0; fm < 2; ++fm)
#pragma unroll
            for (int fn = 0; fn < 2; ++fn)
                acc[fm][fn] = (f32x4){0.f, 0.f, 0.f, 0.f};

#pragma unroll
        for (int kw = 0; kw < 8; ++kw) {
            FragU b[2];
#pragma unroll
            for (int fn = 0; fn < 2; ++fn) {
                const int row = wc * 32 + fn * 16 + r16;
                const int chunk = (kw * 4 + q) ^ (row & 7);
                b[fn].u = *(const uint4*)(buf + row * ROWB + chunk * 16);
            }
#pragma unroll
            for (int fm = 0; fm < 2; ++fm)
#pragma unroll
                for (int fn = 0; fn < 2; ++fn)
                    acc[fm][fn] = __builtin_amdgcn_mfma_f32_16x16x32_bf16(
                        afr[fm][kw].f, b[fn].f, acc[fm][fn], 0, 0, 0);
        }

        // ---- epilogue: sqdist = x2 + c2 - 2*cross; out = exp(scale*sq) ----
        // C/D layout (m89-verified): col = lane&15, row = (lane>>4)*4 + reg
        float* outp = outbase + nt * BN;
#pragma unroll
        for (int fm = 0; fm < 2; ++fm) {
            const int il = il0 + fm * 16;
#pragma unroll
            for (int fn = 0; fn < 2; ++fn) {
                const int j = wc * 32 + fn * 16 + r16;
                const float2 cs = c2s[nt * BN + j];
#pragma unroll
                for (int rg = 0; rg < 4; ++rg) {
                    const float sq = xr[fm][rg] + cs.x - 2.0f * acc[fm][fn][rg];
                    outp[(size_t)(il + rg) * KCENT + j] = __expf(sq * cs.y);
                }
            }
        }

        __syncthreads();  // drains B[nt+1] prefetch (+stores); frees buf for nt+2
    }
}

extern "C" void kernel_launch(void* const* d_in, const int* in_sizes, int n_in,
                              void* d_out, int out_size, void* d_ws, size_t ws_size,
                              hipStream_t stream) {
    const float* x = (const float*)d_in[0];
    const float* centers = (const float*)d_in[1];
    const float* sigmas = (const float*)d_in[2];
    float* out = (float*)d_out;

    const int Brows = in_sizes[0] / DDIM;  // 32768

    // workspace layout: cbf (512 KB) | c2s (8 KB)
    char* ws = (char*)d_ws;
    __bf16* cbf = (__bf16*)ws;
    float2* c2s = (float2*)(ws + (size_t)KCENT * DDIM * 2);

    rbf_prep_c<<<dim3(KCENT / 4), dim3(256), 0, stream>>>(centers, sigmas, cbf, c2s);
    rbf_gemm<<<dim3(Brows / BM), dim3(256), 0, stream>>>(x, cbf, c2s, out);
}